// Round 1
// baseline (1051.232 us; speedup 1.0000x reference)
//
#include <hip/hip_runtime.h>

// xLSTM fused recurrence for MI355X (gfx950).
// Grid: 256 blocks x 128 threads (2 waves). Block b owns batch rows [16b,16b+16).
// Wave w computes gate columns j in [16w, 16w+16) via mfma_f32_16x16x32_bf16.
// h exchanged across waves per step through LDS (time-parity double buffer).
// Precision: f/i gates use hi/lo bf16 splits of x,W,h,R (3-term); o/z plain bf16.

typedef __attribute__((ext_vector_type(8))) short bf16x8;   // 8 bf16 = 4 VGPR
typedef __attribute__((ext_vector_type(4))) float f32x4;    // MFMA C/D

static __device__ __forceinline__ unsigned short f2bf(float f) {
    union { __bf16 b; unsigned short u; } v; v.b = (__bf16)f; return v.u;
}
static __device__ __forceinline__ float bf2f(unsigned short u) {
    union { unsigned int i; float f; } v; v.i = ((unsigned int)u) << 16; return v.f;
}

union fragu { bf16x8 v; unsigned short u[8]; };

#define MFMA(A, B, C) __builtin_amdgcn_mfma_f32_16x16x32_bf16((A), (B), (C), 0, 0, 0)

__global__ __launch_bounds__(128, 1)
void xlstm_fused(const float* __restrict__ x, const int* __restrict__ ticker,
                 const float* __restrict__ wfw, const float* __restrict__ wfb,
                 const float* __restrict__ wiw, const float* __restrict__ wib,
                 const float* __restrict__ wow, const float* __restrict__ wob,
                 const float* __restrict__ wzw, const float* __restrict__ wzb,
                 const float* __restrict__ rfw, const float* __restrict__ riw,
                 const float* __restrict__ rowp, const float* __restrict__ rzw,
                 const float* __restrict__ emb, const float* __restrict__ fcw,
                 const float* __restrict__ fcb, float* __restrict__ out)
{
    const int tid0 = threadIdx.x;
    const int w    = tid0 >> 6;      // wave id (0,1) -> j-half
    const int l    = tid0 & 63;      // lane
    const int lj   = l & 15;         // A-row / D-col index
    const int g4   = l >> 4;         // k-group / D-row group
    const int b0   = blockIdx.x * 16;
    const int jj   = 16 * w + lj;    // output unit owned by this lane (B-frag row)

    // h exchange buffers: [parity][hi/lo][b][k padded to 40 ushorts = 80B (16B-mult)]
    __shared__ __align__(16) unsigned short hbuf[2][2][16][40];
    __shared__ float part[2][16];

    // ---------------- weight fragments (held in VGPRs for whole kernel) ----------
    bf16x8 wxh[4][2];   // x-proj W hi, [gate][k-half]
    bf16x8 wxl[2][2];   // x-proj W lo, f/i only
    bf16x8 wrh[4];      // recurrent R hi
    bf16x8 wrl[2];      // recurrent R lo, f/i only
    float  bias[4];

    {
        const float* wp[4] = { wfw, wiw, wow, wzw };
        const float* bp[4] = { wfb, wib, wob, wzb };
        const float* rp[4] = { rfw, riw, rowp, rzw };
#pragma unroll
        for (int g = 0; g < 4; ++g) {
            bias[g] = bp[g][jj];
#pragma unroll
            for (int kh = 0; kh < 2; ++kh) {
                const float* p = wp[g] + jj * 64 + kh * 32 + g4 * 8;
                fragu h, lo;
#pragma unroll
                for (int e = 0; e < 8; ++e) {
                    float f = p[e];
                    h.u[e]  = f2bf(f);
                    lo.u[e] = f2bf(f - bf2f(h.u[e]));
                }
                wxh[g][kh] = h.v;
                if (g < 2) wxl[g][kh] = lo.v;
            }
            const float* pr = rp[g] + jj * 32 + g4 * 8;
            fragu h, lo;
#pragma unroll
            for (int e = 0; e < 8; ++e) {
                float f = pr[e];
                h.u[e]  = f2bf(f);
                lo.u[e] = f2bf(f - bf2f(h.u[e]));
            }
            wrh[g] = h.v;
            if (g < 2) wrl[g] = lo.v;
        }
    }

    // x addressing: lane reads rows b0+lj, float chunks [8*g4..8*g4+8) and +32
    const float* xrow = x + (size_t)(b0 + lj) * (512 * 64) + g4 * 8;

    float4 pfA0, pfA1, pfA2, pfA3, pfB0, pfB1, pfB2, pfB3;

#define ISSUE_PF(P0, P1, P2, P3, T_) {                                  \
        const float* p_ = xrow + (size_t)(T_) * 64;                     \
        P0 = *(const float4*)(p_ + 0);  P1 = *(const float4*)(p_ + 4);  \
        P2 = *(const float4*)(p_ + 32); P3 = *(const float4*)(p_ + 36); }

#define CVT_X(P0, P1, P2, P3, XH0, XL0, XH1, XL1) {                       \
        float v_[16] = { P0.x, P0.y, P0.z, P0.w, P1.x, P1.y, P1.z, P1.w,  \
                         P2.x, P2.y, P2.z, P2.w, P3.x, P3.y, P3.z, P3.w };\
        fragu h0_, l0_, h1_, l1_;                                         \
        _Pragma("unroll")                                                 \
        for (int e_ = 0; e_ < 8; ++e_) {                                  \
            h0_.u[e_] = f2bf(v_[e_]);                                     \
            l0_.u[e_] = f2bf(v_[e_]     - bf2f(h0_.u[e_]));               \
            h1_.u[e_] = f2bf(v_[e_ + 8]);                                 \
            l1_.u[e_] = f2bf(v_[e_ + 8] - bf2f(h1_.u[e_]));               \
        }                                                                 \
        XH0 = h0_.v; XL0 = l0_.v; XH1 = h1_.v; XL1 = l1_.v; }

    bf16x8 xh0, xl0, xh1, xl1, yh0, yl0, yh1, yl1;
    bf16x8 hfh = {0,0,0,0,0,0,0,0};
    bf16x8 hfl = {0,0,0,0,0,0,0,0};
    float cS0 = 0.f, cS1 = 0.f, cS2 = 0.f, cS3 = 0.f;
    float nS0 = 0.f, nS1 = 0.f, nS2 = 0.f, nS3 = 0.f;
    float hS0 = 0.f, hS1 = 0.f, hS2 = 0.f, hS3 = 0.f;

// elementwise update for one accumulator row r (fp32 throughout, matches reference)
#define EW(PAR, R, AF, AI, AO, AZ, C, N, HS) {                                  \
        float ft_ = fminf((AF), 10.f), it_ = fminf((AI), 10.f);                 \
        float fh_ = __expf(ft_), ih_ = __expf(it_);                             \
        float rd_ = __builtin_amdgcn_rcpf(fh_ + ih_ + 1e-8f);                   \
        float fg_ = fh_ * rd_, ig_ = ih_ * rd_;                                 \
        float og_ = __builtin_amdgcn_rcpf(1.f + __expf(-(AO)));                 \
        float e2_ = __expf(2.f * (AZ));                                         \
        float zg_ = 1.f - 2.f * __builtin_amdgcn_rcpf(e2_ + 1.f);               \
        C = fg_ * C + ig_ * zg_;                                                \
        N = fg_ * N + ig_;                                                      \
        HS = og_ * (C * __builtin_amdgcn_rcpf(N + 1e-8f));                      \
        unsigned short hh_ = f2bf(HS);                                          \
        unsigned short hl_ = f2bf(HS - bf2f(hh_));                              \
        hbuf[PAR][0][4 * g4 + (R)][jj] = hh_;                                   \
        hbuf[PAR][1][4 * g4 + (R)][jj] = hl_; }

#define STEP(PAR, XH0, XL0, XH1, XL1) {                                         \
        f32x4 af = { bias[0], bias[0], bias[0], bias[0] };                      \
        f32x4 ai = { bias[1], bias[1], bias[1], bias[1] };                      \
        f32x4 ao = { bias[2], bias[2], bias[2], bias[2] };                      \
        f32x4 az = { bias[3], bias[3], bias[3], bias[3] };                      \
        /* x-projection: f,i 3-term split; o,z hi only */                       \
        af = MFMA(XH0, wxh[0][0], af);  af = MFMA(XH1, wxh[0][1], af);          \
        af = MFMA(XL0, wxh[0][0], af);  af = MFMA(XL1, wxh[0][1], af);          \
        af = MFMA(XH0, wxl[0][0], af);  af = MFMA(XH1, wxl[0][1], af);          \
        ai = MFMA(XH0, wxh[1][0], ai);  ai = MFMA(XH1, wxh[1][1], ai);          \
        ai = MFMA(XL0, wxh[1][0], ai);  ai = MFMA(XL1, wxh[1][1], ai);          \
        ai = MFMA(XH0, wxl[1][0], ai);  ai = MFMA(XH1, wxl[1][1], ai);          \
        ao = MFMA(XH0, wxh[2][0], ao);  ao = MFMA(XH1, wxh[2][1], ao);          \
        az = MFMA(XH0, wxh[3][0], az);  az = MFMA(XH1, wxh[3][1], az);          \
        /* recurrent: f,i 3-term; o,z hi only */                                \
        af = MFMA(hfh, wrh[0], af); af = MFMA(hfl, wrh[0], af);                 \
        af = MFMA(hfh, wrl[0], af);                                             \
        ai = MFMA(hfh, wrh[1], ai); ai = MFMA(hfl, wrh[1], ai);                 \
        ai = MFMA(hfh, wrl[1], ai);                                             \
        ao = MFMA(hfh, wrh[2], ao);                                             \
        az = MFMA(hfh, wrh[3], az);                                             \
        EW(PAR, 0, af[0], ai[0], ao[0], az[0], cS0, nS0, hS0)                   \
        EW(PAR, 1, af[1], ai[1], ao[1], az[1], cS1, nS1, hS1)                   \
        EW(PAR, 2, af[2], ai[2], ao[2], az[2], cS2, nS2, hS2)                   \
        EW(PAR, 3, af[3], ai[3], ao[3], az[3], cS3, nS3, hS3)                   \
        asm volatile("s_waitcnt lgkmcnt(0)" ::: "memory");                      \
        __builtin_amdgcn_s_barrier();                                           \
        asm volatile("" ::: "memory");                                          \
        { const unsigned short* rh_ = &hbuf[PAR][0][lj][g4 * 8];                \
          const unsigned short* rl_ = &hbuf[PAR][1][lj][g4 * 8];                \
          hfh = *(const bf16x8*)rh_;                                            \
          hfl = *(const bf16x8*)rl_; } }

    // ---------------- pipeline prologue ----------------
    ISSUE_PF(pfA0, pfA1, pfA2, pfA3, 0);
    ISSUE_PF(pfB0, pfB1, pfB2, pfB3, 1);
    CVT_X(pfA0, pfA1, pfA2, pfA3, xh0, xl0, xh1, xl1);   // t=0 frags

    // ---------------- main time loop: 2 steps per iteration ----------------
    for (int itx = 0; itx < 256; ++itx) {
        const int s  = itx * 2;
        const int tA = (s + 2 < 512) ? s + 2 : s;
        ISSUE_PF(pfA0, pfA1, pfA2, pfA3, tA);            // prefetch t=s+2
        STEP(0, xh0, xl0, xh1, xl1);                     // compute t=s
        CVT_X(pfB0, pfB1, pfB2, pfB3, yh0, yl0, yh1, yl1); // frags t=s+1
        const int tB = (s + 3 < 512) ? s + 3 : s + 1;
        ISSUE_PF(pfB0, pfB1, pfB2, pfB3, tB);            // prefetch t=s+3
        STEP(1, yh0, yl0, yh1, yl1);                     // compute t=s+1
        CVT_X(pfA0, pfA1, pfA2, pfA3, xh0, xl0, xh1, xl1); // frags t=s+2
    }

    // ---------------- epilogue: pos = tanh(h.fc_w[:32] + emb.fc_w[32:40] + b) ----
    const float fcj = fcw[jj];
    float p0 = hS0 * fcj, p1 = hS1 * fcj, p2 = hS2 * fcj, p3 = hS3 * fcj;
#pragma unroll
    for (int off = 1; off < 16; off <<= 1) {
        p0 += __shfl_xor(p0, off, 64);
        p1 += __shfl_xor(p1, off, 64);
        p2 += __shfl_xor(p2, off, 64);
        p3 += __shfl_xor(p3, off, 64);
    }
    if (lj == 0) {
        part[w][4 * g4 + 0] = p0;
        part[w][4 * g4 + 1] = p1;
        part[w][4 * g4 + 2] = p2;
        part[w][4 * g4 + 3] = p3;
    }
    __syncthreads();
    if (tid0 < 16) {
        const int b = tid0;
        float sum = part[0][b] + part[1][b] + fcb[0];
        const int tk = ticker[b0 + b];
        const float* ep = emb + (size_t)tk * 8;
#pragma unroll
        for (int k = 0; k < 8; ++k) sum += ep[k] * fcw[32 + k];
        out[b0 + b] = tanhf(sum);
    }
}

extern "C" void kernel_launch(void* const* d_in, const int* in_sizes, int n_in,
                              void* d_out, int out_size, void* d_ws, size_t ws_size,
                              hipStream_t stream)
{
    const float* x      = (const float*)d_in[0];
    const int*   ticker = (const int*)  d_in[1];
    const float* wfw    = (const float*)d_in[2];
    const float* wfb    = (const float*)d_in[3];
    const float* wiw    = (const float*)d_in[4];
    const float* wib    = (const float*)d_in[5];
    const float* wow    = (const float*)d_in[6];
    const float* wob    = (const float*)d_in[7];
    const float* wzw    = (const float*)d_in[8];
    const float* wzb    = (const float*)d_in[9];
    const float* rfw    = (const float*)d_in[10];
    const float* riw    = (const float*)d_in[11];
    const float* rowp   = (const float*)d_in[12];
    const float* rzw    = (const float*)d_in[13];
    const float* emb    = (const float*)d_in[14];
    const float* fcw    = (const float*)d_in[15];
    const float* fcb    = (const float*)d_in[16];

    hipLaunchKernelGGL(xlstm_fused, dim3(4096 / 16), dim3(128), 0, stream,
                       x, ticker, wfw, wfb, wiw, wib, wow, wob, wzw, wzb,
                       rfw, riw, rowp, rzw, emb, fcw, fcb, (float*)d_out);
}